// Round 13
// baseline (212.110 us; speedup 1.0000x reference)
//
#include <hip/hip_runtime.h>
#include <cstdint>

typedef __attribute__((ext_vector_type(4))) float f32x4;
typedef __attribute__((ext_vector_type(8))) short bf16x8;

#define HIDDEN 2880
#define SEQ 2048
#define QKV_N 5120   // 4096 q + 512 k + 512 v
#define WIN 128

__device__ __forceinline__ ushort f2bf(float f) {
  uint32_t u = __builtin_bit_cast(uint32_t, f);
  u += 0x7fff + ((u >> 16) & 1);
  return (ushort)(u >> 16);
}
__device__ __forceinline__ float bf2f(ushort h) {
  uint32_t u = ((uint32_t)h) << 16;
  return __builtin_bit_cast(float, u);
}

// ---------------- f32 -> bf16 elementwise (8/thread) ----------------
__global__ void conv_kernel(const float* __restrict__ in, ushort* __restrict__ out, int n) {
  int i = (blockIdx.x * blockDim.x + threadIdx.x) * 8;
  if (i >= n) return;
  float4 a = *(const float4*)(in + i);
  float4 b = *(const float4*)(in + i + 4);
  bf16x8 o;
  o[0] = (short)f2bf(a.x); o[1] = (short)f2bf(a.y); o[2] = (short)f2bf(a.z); o[3] = (short)f2bf(a.w);
  o[4] = (short)f2bf(b.x); o[5] = (short)f2bf(b.y); o[6] = (short)f2bf(b.z); o[7] = (short)f2bf(b.w);
  *(bf16x8*)(out + i) = o;
}

// ---------------- f32 (R x C) -> bf16 transposed (C x R), 64x64 vectorized ----------------
__global__ __launch_bounds__(256) void tconv2_kernel(const float* __restrict__ in, ushort* __restrict__ out,
                                                     int C, int out_ld, int out_row_off) {
  __shared__ ushort tile[64][68];
  int c0 = blockIdx.x * 64, r0 = blockIdx.y * 64;
  int t = threadIdx.x;
  int lr = t >> 4;          // 0..15
  int lc = (t & 15) * 4;    // 0,4,...,60
#pragma unroll
  for (int i = 0; i < 4; ++i) {
    float4 v = *(const float4*)&in[(size_t)(r0 + i * 16 + lr) * C + c0 + lc];
    ushort4 o;
    o.x = f2bf(v.x); o.y = f2bf(v.y); o.z = f2bf(v.z); o.w = f2bf(v.w);
    *(ushort4*)&tile[i * 16 + lr][lc] = o;
  }
  __syncthreads();
  int rr0 = (t & 7) * 8;
#pragma unroll
  for (int i2 = 0; i2 < 2; ++i2) {
    int cc = i2 * 32 + (t >> 3);
    bf16x8 o;
#pragma unroll
    for (int j = 0; j < 8; ++j) o[j] = (short)tile[rr0 + j][cc];
    *(bf16x8*)&out[(size_t)(out_row_off + c0 + cc) * out_ld + r0 + rr0] = o;
  }
}

__global__ void biascat_kernel(const float* __restrict__ bq, const float* __restrict__ bk,
                               const float* __restrict__ bv, float* __restrict__ out) {
  int i = blockIdx.x * blockDim.x + threadIdx.x;
  if (i >= QKV_N) return;
  float v = (i < 4096) ? bq[i] : (i < 4608) ? bk[i - 4096] : bv[i - 4608];
  out[i] = v;
}

// ---------------- rope cos/sin table: [2048][32] of float2 ----------------
__global__ void ropetab_kernel(float2* __restrict__ tab) {
  int i = blockIdx.x * blockDim.x + threadIdx.x; // 2048*32
  int s = i >> 5, d = i & 31;
  float inv = powf(10000.0f, -(float)d / 32.0f);
  float f = (float)s * inv;
  tab[i] = make_float2(cosf(f), sinf(f));
}

// ---------------- V transpose: qkv V region [2048][512] -> vt [512][2048] ----------------
__global__ __launch_bounds__(256) void vt_kernel(const ushort* __restrict__ qkv, ushort* __restrict__ vt) {
  __shared__ ushort tile[64][80];
  int kv0 = blockIdx.x * 64, d0 = blockIdx.y * 64;
  int t = threadIdx.x;
#pragma unroll
  for (int p = 0; p < 2; ++p) {
    int lr = p * 32 + (t >> 3);
    *(bf16x8*)&tile[lr][(t & 7) * 8] =
        *(const bf16x8*)&qkv[(size_t)(kv0 + lr) * QKV_N + 4608 + d0 + (t & 7) * 8];
  }
  __syncthreads();
#pragma unroll
  for (int p = 0; p < 2; ++p) {
    int dl = p * 32 + (t >> 3);
    bf16x8 o;
#pragma unroll
    for (int jj = 0; jj < 8; ++jj) o[jj] = (short)tile[(t & 7) * 8 + jj][dl];
    *(bf16x8*)&vt[(size_t)(d0 + dl) * 2048 + kv0 + (t & 7) * 8] = o;
  }
}

#define LGKM0()                                              \
  do {                                                       \
    asm volatile("s_waitcnt lgkmcnt(0)" ::: "memory");       \
    __builtin_amdgcn_sched_barrier(0);                       \
  } while (0)
#define WAITV0() asm volatile("s_waitcnt vmcnt(0)" ::: "memory")
#define BAR() __builtin_amdgcn_s_barrier()

// ===================================================================================
// K-split 8-wave MFMA GEMM (QKV): block 128 x 320, waves = 4 wn x 2 wk.
// Wave tile = ALL 128 rows x 80 cols at K-half kh=wk (32 of each 64 K-tile).
// Read volume/CU-tile: B read by exactly 1 wave, A by 4 -> 104 KB vs 144 KB of the
// 2m x 2n layout (the additive LDS-read term is the measured bottleneck).
// LDS/buffer: [Akh0 8K|Akh1 8K|Bkh0 20K|Bkh1 20K] = 56 KB, dbuf 112 KB, 1 block/CU,
// 8 waves (2/SIMD). Staging uniform 7 issues/wave. Drain-0 + 1 barrier per tile
// (round-8 proven semantics). Epilogue: wk1 dumps acc to LDS (2 chunks), wk0 adds,
// wk0 writes C (+bias). Grid = 16m x 16n = 256 (exactly 1/CU), XCD-swizzled.
// ===================================================================================
__global__ __launch_bounds__(512, 2) void gemmks_kernel(
    const ushort* __restrict__ A, const ushort* __restrict__ Bt,
    const float* __restrict__ bias, ushort* __restrict__ Cv,
    int K, int lda, int ldb, int ldc) {
  constexpr int BUFBYTES = 57344;  // 16K A + 40K B
  __shared__ __align__(16) char ldsbuf[2 * BUFBYTES];

  const int cpx = gridDim.x >> 3;
  const int wg = ((int)blockIdx.x & 7) * cpx + ((int)blockIdx.x >> 3);
  const int mtile = wg & 15, ntile = wg >> 4;
  const int m0 = mtile * 128, n0 = ntile * 320;

  const int tid = threadIdx.x, wv = tid >> 6, l = tid & 63;
  const int wn = wv & 3, wk = wv >> 2;
  const int r = l & 15, g = l >> 4;

  // staging source: pre-swizzled chunk (linear LDS dest, inv-swz source)
  const int c = l ^ ((l >> 3) & 3);
  const ushort* gA0 = A + (size_t)(m0 + (c >> 2)) * lda + (c & 3) * 8;
  const ushort* gB0 = Bt + (size_t)(n0 + (c >> 2)) * ldb + (c & 3) * 8;

  // fragment read offsets (XOR swizzle on addr bits 4-5)
  const int gsw = (g * 16) ^ (((r >> 1) & 3) << 4);
  const int aOff = r * 64 + gsw;              // + mi*1024 + wk*8192
  const int bOff = (wn * 80 + r) * 64 + gsw;  // + nf*1024 + 16384 + wk*20480

  auto sA = [&](int nb, int kg) {  // 16 chunks: kh=cid>>3, rowchunk=cid&7
#pragma unroll
    for (int j = 0; j < 2; ++j) {
      int cid = wv * 2 + j;
      int kh = cid >> 3, rc = cid & 7;
      __builtin_amdgcn_global_load_lds(
          (const __attribute__((address_space(1))) void*)(const void*)(gA0 + (size_t)rc * 16 * lda + kg + kh * 32),
          (__attribute__((address_space(3))) void*)&ldsbuf[nb * BUFBYTES + kh * 8192 + rc * 1024], 16, 0, 0);
    }
  };
  auto sB = [&](int nb, int kg) {  // 40 chunks: kh=cid/20, colchunk=cid%20
#pragma unroll
    for (int j = 0; j < 5; ++j) {
      int cid = wv * 5 + j;
      int kh = cid / 20, cc = cid - (cid / 20) * 20;
      __builtin_amdgcn_global_load_lds(
          (const __attribute__((address_space(1))) void*)(const void*)(gB0 + (size_t)cc * 16 * ldb + kg + kh * 32),
          (__attribute__((address_space(3))) void*)&ldsbuf[nb * BUFBYTES + 16384 + kh * 20480 + cc * 1024],
          16, 0, 0);
    }
  };

  f32x4 acc[8][5] = {};
  const int nt = K >> 6;

  sA(0, 0); sB(0, 0);
  WAITV0();
  BAR();

  for (int t = 0; t < nt; ++t) {
    const int bufOff = (t & 1) * BUFBYTES;
    const int nb = (t & 1) ^ 1;
    bf16x8 aq[8], bq[5];
    const int khA = bufOff + wk * 8192;
    const int khB = bufOff + 16384 + wk * 20480;
#pragma unroll
    for (int nf = 0; nf < 5; ++nf)
      bq[nf] = *(const bf16x8*)&ldsbuf[khB + bOff + nf * 1024];
#pragma unroll
    for (int mi = 0; mi < 8; ++mi)
      aq[mi] = *(const bf16x8*)&ldsbuf[khA + aOff + mi * 1024];
    if (t + 1 < nt) { sA(nb, (t + 1) * 64); sB(nb, (t + 1) * 64); }
    LGKM0();
    __builtin_amdgcn_s_setprio(1);
#pragma unroll
    for (int mi = 0; mi < 8; ++mi)
#pragma unroll
      for (int nf = 0; nf < 5; ++nf)
        acc[mi][nf] = __builtin_amdgcn_mfma_f32_16x16x32_bf16(aq[mi], bq[nf], acc[mi][nf], 0, 0, 0);
    __builtin_amdgcn_s_setprio(0);
    WAITV0();
    BAR();
  }

  // k-split reduction: wk1 -> LDS (2 chunks of 4 mi, 80 KB), wk0 adds
#pragma unroll
  for (int ch = 0; ch < 2; ++ch) {
    if (wk == 1) {
#pragma unroll
      for (int mi = 0; mi < 4; ++mi)
#pragma unroll
        for (int nf = 0; nf < 5; ++nf)
          *(f32x4*)&ldsbuf[wn * 20480 + (mi * 5 + nf) * 1024 + l * 16] = acc[ch * 4 + mi][nf];
    }
    __syncthreads();
    if (wk == 0) {
#pragma unroll
      for (int mi = 0; mi < 4; ++mi)
#pragma unroll
        for (int nf = 0; nf < 5; ++nf) {
          f32x4 o = *(const f32x4*)&ldsbuf[wn * 20480 + (mi * 5 + nf) * 1024 + l * 16];
#pragma unroll
          for (int j = 0; j < 4; ++j) acc[ch * 4 + mi][nf][j] += o[j];
        }
    }
    __syncthreads();
  }

  if (wk == 0) {
#pragma unroll
    for (int mi = 0; mi < 8; ++mi)
#pragma unroll
      for (int nf = 0; nf < 5; ++nf) {
        int cc = n0 + wn * 80 + nf * 16 + r;
        float b = bias[cc];
#pragma unroll
        for (int j = 0; j < 4; ++j) {
          int rrow = m0 + mi * 16 + g * 4 + j;
          Cv[(size_t)rrow * ldc + cc] = f2bf(acc[mi][nf][j] + b);
        }
      }
  }
}

// ===================================================================================
// 4-wave MFMA GEMM (O-proj; round-8 measured-best structure: drain-0, 2 blocks/CU).
// ===================================================================================
template <int BN, bool OUT_BF16>
__global__ __launch_bounds__(256, 2) void gemm4w_kernel(
    const ushort* __restrict__ A, const ushort* __restrict__ Bt,
    const float* __restrict__ bias, void* __restrict__ Cv,
    int K, int lda, int ldb, int ldc) {
  constexpr int NFRAG = BN / 32;
  constexpr int BHALF = BN * 64;
  constexpr int BCHUNKS = BHALF / 1024;
  constexpr int BUFBYTES = 16384 + 2 * BHALF;
  __shared__ __align__(16) char ldsbuf[2 * BUFBYTES];

  const int cpx = gridDim.x >> 3;
  const int wg = ((int)blockIdx.x & 7) * cpx + ((int)blockIdx.x >> 3);
  const int mtile = wg & 15, ntile = wg >> 4;
  const int m0 = mtile * 128, n0 = ntile * BN;

  const int tid = threadIdx.x, wv = tid >> 6, l = tid & 63;
  const int wm = wv >> 1, wn = wv & 1;
  const int r = l & 15, g = l >> 4;

  const int c = l ^ ((l >> 3) & 3);
  const ushort* gA0 = A + (size_t)(m0 + (c >> 2)) * lda + (c & 3) * 8;
  const ushort* gB0 = Bt + (size_t)(n0 + (c >> 2)) * ldb + (c & 3) * 8;

  const int gsw = (g * 16) ^ (((r >> 1) & 3) << 4);
  const int aOff = (wm * 64 + r) * 64 + gsw;
  const int bOff = (wn * (NFRAG * 16) + r) * 64 + gsw;

  auto sA = [&](int nb, int kg, int kh) {
#pragma unroll
    for (int j = 0; j < 2; ++j) {
      int cid = j * 4 + wv;
      __builtin_amdgcn_global_load_lds(
          (const __attribute__((address_space(1))) void*)(const void*)(gA0 + (size_t)cid * 16 * lda + kg),
          (__attribute__((address_space(3))) void*)&ldsbuf[nb * BUFBYTES + kh * 8192 + cid * 1024], 16, 0, 0);
    }
  };
  auto sB = [&](int nb, int kg, int kh) {
#pragma unroll
    for (int j = 0; j < (BCHUNKS + 3) / 4; ++j) {
      int cid = j * 4 + wv;
      if (cid < BCHUNKS)
        __builtin_amdgcn_global_load_lds(
            (const __attribute__((address_space(1))) void*)(const void*)(gB0 + (size_t)cid * 16 * ldb + kg),
            (__attribute__((address_space(3))) void*)&ldsbuf[nb * BUFBYTES + 16384 + kh * BHALF + cid * 1024],
            16, 0, 0);
    }
  };

  f32x4 acc[4][NFRAG] = {};
  const int nt = K >> 6;

  sA(0, 0, 0); sA(0, 32, 1); sB(0, 0, 0); sB(0, 32, 1);
  WAITV0();
  BAR();

  for (int t = 0; t < nt; ++t) {
    const int bufOff = (t & 1) * BUFBYTES;
    const int nb = (t & 1) ^ 1;
    if (t + 1 < nt) {
      const int kn = (t + 1) * 64;
      sA(nb, kn, 0); sA(nb, kn + 32, 1);
      sB(nb, kn, 0); sB(nb, kn + 32, 1);
    }
#pragma unroll
    for (int kh = 0; kh < 2; ++kh) {
      bf16x8 aq[4], bq[NFRAG];
#pragma unroll
      for (int nf = 0; nf < NFRAG; ++nf)
        bq[nf] = *(const bf16x8*)&ldsbuf[bufOff + 16384 + kh * BHALF + bOff + nf * 1024];
#pragma unroll
      for (int mi = 0; mi < 4; ++mi)
        aq[mi] = *(const bf16x8*)&ldsbuf[bufOff + kh * 8192 + aOff + mi * 1024];
      LGKM0();
      __builtin_amdgcn_s_setprio(1);
#pragma unroll
      for (int mi = 0; mi < 4; ++mi)
#pragma unroll
        for (int nf = 0; nf < NFRAG; ++nf)
          acc[mi][nf] = __builtin_amdgcn_mfma_f32_16x16x32_bf16(aq[mi], bq[nf], acc[mi][nf], 0, 0, 0);
      __builtin_amdgcn_s_setprio(0);
    }
    WAITV0();
    BAR();
  }

#pragma unroll
  for (int mf2 = 0; mf2 < 4; ++mf2) {
#pragma unroll
    for (int nf = 0; nf < NFRAG; ++nf) {
      int cc = n0 + wn * (NFRAG * 16) + nf * 16 + r;
      float b = bias[cc];
#pragma unroll
      for (int j = 0; j < 4; ++j) {
        int rrow = m0 + wm * 64 + mf2 * 16 + g * 4 + j;
        float v = acc[mf2][nf][j] + b;
        if (OUT_BF16) ((ushort*)Cv)[(size_t)rrow * ldc + cc] = f2bf(v);
        else ((float*)Cv)[(size_t)rrow * ldc + cc] = v;
      }
    }
  }
}

// ---------------- attention with fused RoPE: block = (32 q rows) x (kv head) ----------------
__global__ __launch_bounds__(512, 4) void attn_kernel(
    const ushort* __restrict__ qkv, const ushort* __restrict__ vt,
    const float* __restrict__ sinks, const float2* __restrict__ tab,
    ushort* __restrict__ out) {
  __shared__ __align__(16) char lds[54272];
  const int kh = blockIdx.y;
  const int q0 = blockIdx.x * 32;
  const int kvw0 = q0 - 128;
  const int tid = threadIdx.x, w = tid >> 6, l = tid & 63;
  const int r = l & 15, g = l >> 4;
  const int h = kh * 8 + w;

  if (tid < 256) ((uint32_t*)(lds + 40960))[tid] = 0;

#pragma unroll
  for (int it = 0; it < 4; ++it) {
    int c = it * 512 + tid;
    if (c < 640) {  // K pair: row, chunks (ch, ch+4) = rope partners (d, d+32)
      int row = c >> 2, ch = c & 3;
      int kv = kvw0 + row;
      bf16x8 v1 = {}, v2 = {};
      if (kv >= 0) {
        const ushort* kb = &qkv[(size_t)kv * QKV_N + 4096 + kh * 64 + ch * 8];
        bf16x8 x1 = *(const bf16x8*)kb;
        bf16x8 x2 = *(const bf16x8*)(kb + 32);
#pragma unroll
        for (int i = 0; i < 8; ++i) {
          float2 cs = tab[(kv << 5) + ch * 8 + i];
          float a = bf2f((ushort)x1[i]), b = bf2f((ushort)x2[i]);
          v1[i] = (short)f2bf(a * cs.x - b * cs.y);
          v2[i] = (short)f2bf(b * cs.x + a * cs.y);
        }
      }
      int b1 = (row * 128 + ch * 16) ^ ((row & 7) << 4);
      int b2 = (row * 128 + (ch + 4) * 16) ^ ((row & 7) << 4);
      *(bf16x8*)(lds + b1) = v1;
      *(bf16x8*)(lds + b2) = v2;
    } else if (c < 1920) {  // VT chunk
      int cv = c - 640;
      int row = cv / 20, ch = cv - (cv / 20) * 20;
      int kv = kvw0 + ch * 8;
      bf16x8 vv = {};
      if (kv >= 0) vv = *(const bf16x8*)&vt[(size_t)(kh * 64 + row) * 2048 + kv];
      int byte = (row * 320 + ch * 16) ^ ((row & 7) << 4);
      *(bf16x8*)(lds + 20480 + byte) = vv;
    }
  }
  __syncthreads();

  char* Pw = lds + 41984 + w * 1536;
  const float snk = sinks[h];

#pragma unroll
  for (int si = 0; si < 2; ++si) {
    const ushort* qb = &qkv[(size_t)(q0 + si * 16 + r) * QKV_N + h * 64 + g * 8];
    bf16x8 qf0 = *(const bf16x8*)qb;
    bf16x8 qf1 = *(const bf16x8*)(qb + 32);
    {  // fused Q RoPE
      int s = q0 + si * 16 + r;
      bf16x8 t0, t1;
#pragma unroll
      for (int i = 0; i < 8; ++i) {
        float2 cs = tab[(s << 5) + g * 8 + i];
        float a = bf2f((ushort)qf0[i]), b = bf2f((ushort)qf1[i]);
        t0[i] = (short)f2bf(a * cs.x - b * cs.y);
        t1[i] = (short)f2bf(b * cs.x + a * cs.y);
      }
      qf0 = t0; qf1 = t1;
    }

    f32x4 S[9];
    float mx[4] = {-3e30f, -3e30f, -3e30f, -3e30f};
#pragma unroll
    for (int tt = 0; tt < 9; ++tt) {
      int kvloc = (si + tt) * 16 + r;
      int b0 = (kvloc * 128 + g * 16) ^ ((kvloc & 7) << 4);
      int b1 = (kvloc * 128 + 64 + g * 16) ^ ((kvloc & 7) << 4);
      bf16x8 kf0 = *(const bf16x8*)(lds + b0);
      bf16x8 kf1 = *(const bf16x8*)(lds + b1);
      f32x4 s = {};
      s = __builtin_amdgcn_mfma_f32_16x16x32_bf16(qf0, kf0, s, 0, 0, 0);
      s = __builtin_amdgcn_mfma_f32_16x16x32_bf16(qf1, kf1, s, 0, 0, 0);
      int kvc = kvw0 + kvloc;
#pragma unroll
      for (int j = 0; j < 4; ++j) {
        int qr = q0 + si * 16 + g * 4 + j;
        bool valid = (kvc >= 0) && (kvc <= qr) && (kvc >= qr - WIN);
        float v = valid ? s[j] * 0.125f : -1e30f;
        s[j] = v;
        mx[j] = fmaxf(mx[j], v);
      }
      S[tt] = s;
    }
#pragma unroll
    for (int off = 1; off < 16; off <<= 1)
#pragma unroll
      for (int j = 0; j < 4; ++j) mx[j] = fmaxf(mx[j], __shfl_xor(mx[j], off, 64));
    float m[4], sum[4] = {0, 0, 0, 0};
#pragma unroll
    for (int j = 0; j < 4; ++j) m[j] = fmaxf(mx[j], snk);
#pragma unroll
    for (int tt = 0; tt < 9; ++tt)
#pragma unroll
      for (int j = 0; j < 4; ++j) {
        float p = (S[tt][j] > -1e29f) ? __expf(S[tt][j] - m[j]) : 0.0f;
        S[tt][j] = p;
        sum[j] += p;
      }
#pragma unroll
    for (int off = 1; off < 16; off <<= 1)
#pragma unroll
      for (int j = 0; j < 4; ++j) sum[j] += __shfl_xor(sum[j], off, 64);
    float rinv[4];
#pragma unroll
    for (int j = 0; j < 4; ++j) rinv[j] = 1.0f / (sum[j] + __expf(snk - m[j]));

    f32x4 acc[4] = {};
#pragma unroll
    for (int ks = 0; ks < 5; ++ks) {
#pragma unroll
      for (int c2 = 0; c2 < 2; ++c2) {
        int tt = 2 * ks + c2;
#pragma unroll
        for (int j = 0; j < 4; ++j) {
          float pv = (tt <= 8) ? S[tt][j] * rinv[j] : 0.0f;
          *(ushort*)(Pw + ((g * 4 + j) * 48 + c2 * 16 + r) * 2) = f2bf(pv);
        }
      }
      bf16x8 pa = *(const bf16x8*)(Pw + (r * 48 + g * 8) * 2);
#pragma unroll
      for (int ni = 0; ni < 4; ++ni) {
        int row = ni * 16 + r;
        int byte = (row * 320 + (si * 16 + ks * 32 + g * 8) * 2) ^ ((row & 7) << 4);
        bf16x8 vb = *(const bf16x8*)(lds + 20480 + byte);
        acc[ni] = __builtin_amdgcn_mfma_f32_16x16x32_bf16(pa, vb, acc[ni], 0, 0, 0);
      }
    }
#pragma unroll
    for (int ni = 0; ni < 4; ++ni)
#pragma unroll
      for (int j = 0; j < 4; ++j)
        out[(size_t)(q0 + si * 16 + g * 4 + j) * 4096 + h * 64 + ni * 16 + r] = f2bf(acc[ni][j]);
  }
}

extern "C" void kernel_launch(void* const* d_in, const int* in_sizes, int n_in,
                              void* d_out, int out_size, void* d_ws, size_t ws_size,
                              hipStream_t stream) {
  const float* hs = (const float*)d_in[0];
  const float* Wq = (const float*)d_in[1];
  const float* bq = (const float*)d_in[2];
  const float* Wk = (const float*)d_in[3];
  const float* bk = (const float*)d_in[4];
  const float* Wv = (const float*)d_in[5];
  const float* bv = (const float*)d_in[6];
  const float* Wo = (const float*)d_in[7];
  const float* bo = (const float*)d_in[8];
  const float* sinks = (const float*)d_in[9];
  float* out = (float*)d_out;

  char* ws = (char*)d_ws;
  ushort* hs_bf   = (ushort*)(ws + 0);            // 2048x2880 bf16      11,796,480 B
  ushort* vt_g    = (ushort*)(ws + 0);            // 512x2048  bf16 (reuses hs_bf after QKV GEMM)
  ushort* wqkv_t  = (ushort*)(ws + 11796480);     // 5120x2880 bf16      29,491,200 B
  ushort* attn    = (ushort*)(ws + 11796480);     // 2048x4096 bf16 (reuses wqkv_t after QKV GEMM)
  ushort* wo_t    = (ushort*)(ws + 41287680);     // 2880x4096 bf16      23,592,960 B
  ushort* qkv     = (ushort*)(ws + 66453504);     // 2048x5120 bf16      20,971,520 B
  float*  bias_all= (float*)(ws + 87425024);      // 5120 f32
  float2* tab     = (float2*)(ws + 87445504);     // 2048x32 float2

  // prep: conversions / transposes / tables
  conv_kernel<<<5898240 / 8 / 256, 256, 0, stream>>>(hs, hs_bf, 5898240);
  tconv2_kernel<<<dim3(64, 45), 256, 0, stream>>>(Wq, wqkv_t, 4096, 2880, 0);
  tconv2_kernel<<<dim3(8, 45), 256, 0, stream>>>(Wk, wqkv_t, 512, 2880, 4096);
  tconv2_kernel<<<dim3(8, 45), 256, 0, stream>>>(Wv, wqkv_t, 512, 2880, 4608);
  tconv2_kernel<<<dim3(45, 64), 256, 0, stream>>>(Wo, wo_t, 2880, 4096, 0);
  biascat_kernel<<<20, 256, 0, stream>>>(bq, bk, bv, bias_all);
  ropetab_kernel<<<2048 * 32 / 256, 256, 0, stream>>>(tab);

  // QKV projection (k-split 8-wave): [2048x2880] x [2880x5120] -> qkv. 16m x 16n = 256 wg
  gemmks_kernel<<<256, 512, 0, stream>>>(hs_bf, wqkv_t, bias_all, qkv,
                                         2880, 2880, 2880, 5120);
  // V transpose (into dead hs_bf region)
  vt_kernel<<<dim3(32, 8), 256, 0, stream>>>(qkv, vt_g);
  // attention with fused RoPE (into dead wqkv_t region)
  attn_kernel<<<dim3(64, 8), 512, 0, stream>>>(qkv, vt_g, sinks, tab, attn);
  // output projection: [2048x4096] x [4096x2880] -> out (f32, +bo). 16m x 18n = 288 wg
  gemm4w_kernel<160, false><<<288, 256, 0, stream>>>(attn, wo_t, bo, out,
                                                     4096, 4096, 4096, 2880);
}

// Round 14
// 191.616 us; speedup vs baseline: 1.1069x; 1.1069x over previous
//
#include <hip/hip_runtime.h>
#include <cstdint>

typedef __attribute__((ext_vector_type(4))) float f32x4;
typedef __attribute__((ext_vector_type(8))) short bf16x8;

#define HIDDEN 2880
#define SEQ 2048
#define QKV_N 5120   // 4096 q + 512 k + 512 v
#define WIN 128

__device__ __forceinline__ ushort f2bf(float f) {
  uint32_t u = __builtin_bit_cast(uint32_t, f);
  u += 0x7fff + ((u >> 16) & 1);
  return (ushort)(u >> 16);
}
__device__ __forceinline__ float bf2f(ushort h) {
  uint32_t u = ((uint32_t)h) << 16;
  return __builtin_bit_cast(float, u);
}

// ---------------- fused prep: conv + 4x transpose-conv + biascat + ropetab ----------------
// block ranges (256 threads each):
//   [0,2880)      conv hs -> hs_bf (8 elems/thread, 2048/block)
//   [2880,5760)   tconv Wq  (64 x 45 tiles)
//   [5760,6120)   tconv Wk  (8 x 45)
//   [6120,6480)   tconv Wv  (8 x 45)
//   [6480,9360)   tconv Wo  (45 x 64)
//   [9360,9380)   biascat (20)
//   [9380,9636)   ropetab (256)
__device__ __forceinline__ void tconv_tile(const float* __restrict__ in, ushort* __restrict__ out,
                                           int C, int out_ld, int out_row_off,
                                           int bx, int by, int t, ushort (*tile)[68]) {
  int c0 = bx * 64, r0 = by * 64;
  int lr = t >> 4;          // 0..15
  int lc = (t & 15) * 4;    // 0,4,...,60
#pragma unroll
  for (int i = 0; i < 4; ++i) {
    float4 v = *(const float4*)&in[(size_t)(r0 + i * 16 + lr) * C + c0 + lc];
    ushort4 o;
    o.x = f2bf(v.x); o.y = f2bf(v.y); o.z = f2bf(v.z); o.w = f2bf(v.w);
    *(ushort4*)&tile[i * 16 + lr][lc] = o;
  }
  __syncthreads();
  int rr0 = (t & 7) * 8;
#pragma unroll
  for (int i2 = 0; i2 < 2; ++i2) {
    int cc = i2 * 32 + (t >> 3);
    bf16x8 o;
#pragma unroll
    for (int j = 0; j < 8; ++j) o[j] = (short)tile[rr0 + j][cc];
    *(bf16x8*)&out[(size_t)(out_row_off + c0 + cc) * out_ld + r0 + rr0] = o;
  }
}

__global__ __launch_bounds__(256) void prep_kernel(
    const float* __restrict__ hs, const float* __restrict__ Wq, const float* __restrict__ Wk,
    const float* __restrict__ Wv, const float* __restrict__ Wo,
    const float* __restrict__ bq, const float* __restrict__ bk, const float* __restrict__ bv,
    ushort* __restrict__ hs_bf, ushort* __restrict__ wqkv_t, ushort* __restrict__ wo_t,
    float* __restrict__ bias_all, float2* __restrict__ tab) {
  __shared__ ushort tile[64][68];
  const int b = blockIdx.x, t = threadIdx.x;
  if (b < 2880) {  // conv hs -> bf16
    int i = (b * 256 + t) * 8;
    float4 a = *(const float4*)(hs + i);
    float4 c = *(const float4*)(hs + i + 4);
    bf16x8 o;
    o[0] = (short)f2bf(a.x); o[1] = (short)f2bf(a.y); o[2] = (short)f2bf(a.z); o[3] = (short)f2bf(a.w);
    o[4] = (short)f2bf(c.x); o[5] = (short)f2bf(c.y); o[6] = (short)f2bf(c.z); o[7] = (short)f2bf(c.w);
    *(bf16x8*)(hs_bf + i) = o;
  } else if (b < 5760) {  // Wq transpose
    int idx = b - 2880;
    tconv_tile(Wq, wqkv_t, 4096, 2880, 0, idx & 63, idx >> 6, t, tile);
  } else if (b < 6120) {  // Wk
    int idx = b - 5760;
    tconv_tile(Wk, wqkv_t, 512, 2880, 4096, idx & 7, idx >> 3, t, tile);
  } else if (b < 6480) {  // Wv
    int idx = b - 6120;
    tconv_tile(Wv, wqkv_t, 512, 2880, 4608, idx & 7, idx >> 3, t, tile);
  } else if (b < 9360) {  // Wo transpose
    int idx = b - 6480;
    tconv_tile(Wo, wo_t, 2880, 4096, 0, idx % 45, idx / 45, t, tile);
  } else if (b < 9380) {  // biascat
    int i = (b - 9360) * 256 + t;
    if (i < QKV_N) {
      float v = (i < 4096) ? bq[i] : (i < 4608) ? bk[i - 4096] : bv[i - 4608];
      bias_all[i] = v;
    }
  } else {  // ropetab
    int i = (b - 9380) * 256 + t;  // 2048*32 = 65536
    int s = i >> 5, d = i & 31;
    float inv = powf(10000.0f, -(float)d / 32.0f);
    float f = (float)s * inv;
    tab[i] = make_float2(cosf(f), sinf(f));
  }
}

// ---------------- V transpose: qkv V region [2048][512] -> vt [512][2048] ----------------
__global__ __launch_bounds__(256) void vt_kernel(const ushort* __restrict__ qkv, ushort* __restrict__ vt) {
  __shared__ ushort tile[64][80];
  int kv0 = blockIdx.x * 64, d0 = blockIdx.y * 64;
  int t = threadIdx.x;
#pragma unroll
  for (int p = 0; p < 2; ++p) {
    int lr = p * 32 + (t >> 3);
    *(bf16x8*)&tile[lr][(t & 7) * 8] =
        *(const bf16x8*)&qkv[(size_t)(kv0 + lr) * QKV_N + 4608 + d0 + (t & 7) * 8];
  }
  __syncthreads();
#pragma unroll
  for (int p = 0; p < 2; ++p) {
    int dl = p * 32 + (t >> 3);
    bf16x8 o;
#pragma unroll
    for (int jj = 0; jj < 8; ++jj) o[jj] = (short)tile[(t & 7) * 8 + jj][dl];
    *(bf16x8*)&vt[(size_t)(d0 + dl) * 2048 + kv0 + (t & 7) * 8] = o;
  }
}

#define LGKM0()                                              \
  do {                                                       \
    asm volatile("s_waitcnt lgkmcnt(0)" ::: "memory");       \
    __builtin_amdgcn_sched_barrier(0);                       \
  } while (0)
#define WAITV0() asm volatile("s_waitcnt vmcnt(0)" ::: "memory")
#define BAR() __builtin_amdgcn_s_barrier()

// ===================================================================================
// 4-wave MFMA GEMM (measured-best structure: drain-0, 2 blocks/CU, round 11 = 73 us).
// A (MxK bf16 rm), Bt (NxK bf16 rm). Block tile 128 x BN, 4 waves (2m x 2n),
// wave tile 64 x (BN/2). LDS/buffer: [Ak0 8K|Ak1 8K|Bk0|Bk1], 64B row stride,
// XOR swizzle on addr bits 4-5 (stage: linear LDS dest + pre-swizzled global source).
// Per tile t: issue ALL stages for t+1 -> nbuf; 2x {9 ds_reads; lgkm0; MFMA(setprio)};
// vmcnt(0); s_barrier. Grid = 16 m-tiles x (N/BN), XCD-swizzled n-major.
// ===================================================================================
template <int BN, bool OUT_BF16>
__global__ __launch_bounds__(256, 2) void gemm4w_kernel(
    const ushort* __restrict__ A, const ushort* __restrict__ Bt,
    const float* __restrict__ bias, void* __restrict__ Cv,
    int K, int lda, int ldb, int ldc) {
  constexpr int NFRAG = BN / 32;
  constexpr int BHALF = BN * 64;
  constexpr int BCHUNKS = BHALF / 1024;
  constexpr int BUFBYTES = 16384 + 2 * BHALF;
  __shared__ __align__(16) char ldsbuf[2 * BUFBYTES];

  const int cpx = gridDim.x >> 3;
  const int wg = ((int)blockIdx.x & 7) * cpx + ((int)blockIdx.x >> 3);
  const int mtile = wg & 15, ntile = wg >> 4;
  const int m0 = mtile * 128, n0 = ntile * BN;

  const int tid = threadIdx.x, wv = tid >> 6, l = tid & 63;
  const int wm = wv >> 1, wn = wv & 1;
  const int r = l & 15, g = l >> 4;

  const int c = l ^ ((l >> 3) & 3);
  const ushort* gA0 = A + (size_t)(m0 + (c >> 2)) * lda + (c & 3) * 8;
  const ushort* gB0 = Bt + (size_t)(n0 + (c >> 2)) * ldb + (c & 3) * 8;

  const int gsw = (g * 16) ^ (((r >> 1) & 3) << 4);
  const int aOff = (wm * 64 + r) * 64 + gsw;
  const int bOff = (wn * (NFRAG * 16) + r) * 64 + gsw;

  auto sA = [&](int nb, int kg, int kh) {
#pragma unroll
    for (int j = 0; j < 2; ++j) {
      int cid = j * 4 + wv;
      __builtin_amdgcn_global_load_lds(
          (const __attribute__((address_space(1))) void*)(const void*)(gA0 + (size_t)cid * 16 * lda + kg),
          (__attribute__((address_space(3))) void*)&ldsbuf[nb * BUFBYTES + kh * 8192 + cid * 1024], 16, 0, 0);
    }
  };
  auto sB = [&](int nb, int kg, int kh) {
#pragma unroll
    for (int j = 0; j < (BCHUNKS + 3) / 4; ++j) {
      int cid = j * 4 + wv;
      if (cid < BCHUNKS)
        __builtin_amdgcn_global_load_lds(
            (const __attribute__((address_space(1))) void*)(const void*)(gB0 + (size_t)cid * 16 * ldb + kg),
            (__attribute__((address_space(3))) void*)&ldsbuf[nb * BUFBYTES + 16384 + kh * BHALF + cid * 1024],
            16, 0, 0);
    }
  };

  f32x4 acc[4][NFRAG] = {};
  const int nt = K >> 6;

  sA(0, 0, 0); sA(0, 32, 1); sB(0, 0, 0); sB(0, 32, 1);
  WAITV0();
  BAR();

  for (int t = 0; t < nt; ++t) {
    const int bufOff = (t & 1) * BUFBYTES;
    const int nb = (t & 1) ^ 1;
    if (t + 1 < nt) {
      const int kn = (t + 1) * 64;
      sA(nb, kn, 0); sA(nb, kn + 32, 1);
      sB(nb, kn, 0); sB(nb, kn + 32, 1);
    }
#pragma unroll
    for (int kh = 0; kh < 2; ++kh) {
      bf16x8 aq[4], bq[NFRAG];
#pragma unroll
      for (int nf = 0; nf < NFRAG; ++nf)
        bq[nf] = *(const bf16x8*)&ldsbuf[bufOff + 16384 + kh * BHALF + bOff + nf * 1024];
#pragma unroll
      for (int mi = 0; mi < 4; ++mi)
        aq[mi] = *(const bf16x8*)&ldsbuf[bufOff + kh * 8192 + aOff + mi * 1024];
      LGKM0();
      __builtin_amdgcn_s_setprio(1);
#pragma unroll
      for (int mi = 0; mi < 4; ++mi)
#pragma unroll
        for (int nf = 0; nf < NFRAG; ++nf)
          acc[mi][nf] = __builtin_amdgcn_mfma_f32_16x16x32_bf16(aq[mi], bq[nf], acc[mi][nf], 0, 0, 0);
      __builtin_amdgcn_s_setprio(0);
    }
    WAITV0();
    BAR();
  }

#pragma unroll
  for (int mf2 = 0; mf2 < 4; ++mf2) {
#pragma unroll
    for (int nf = 0; nf < NFRAG; ++nf) {
      int cc = n0 + wn * (NFRAG * 16) + nf * 16 + r;
      float b = bias[cc];
#pragma unroll
      for (int j = 0; j < 4; ++j) {
        int rrow = m0 + wm * 64 + mf2 * 16 + g * 4 + j;
        float v = acc[mf2][nf][j] + b;
        if (OUT_BF16) ((ushort*)Cv)[(size_t)rrow * ldc + cc] = f2bf(v);
        else ((float*)Cv)[(size_t)rrow * ldc + cc] = v;
      }
    }
  }
}

// ---------------- attention with fused RoPE: block = (32 q rows) x (kv head) ----------------
__global__ __launch_bounds__(512, 4) void attn_kernel(
    const ushort* __restrict__ qkv, const ushort* __restrict__ vt,
    const float* __restrict__ sinks, const float2* __restrict__ tab,
    ushort* __restrict__ out) {
  __shared__ __align__(16) char lds[54272];
  const int kh = blockIdx.y;
  const int q0 = blockIdx.x * 32;
  const int kvw0 = q0 - 128;
  const int tid = threadIdx.x, w = tid >> 6, l = tid & 63;
  const int r = l & 15, g = l >> 4;
  const int h = kh * 8 + w;

  if (tid < 256) ((uint32_t*)(lds + 40960))[tid] = 0;

#pragma unroll
  for (int it = 0; it < 4; ++it) {
    int c = it * 512 + tid;
    if (c < 640) {  // K pair: row, chunks (ch, ch+4) = rope partners (d, d+32)
      int row = c >> 2, ch = c & 3;
      int kv = kvw0 + row;
      bf16x8 v1 = {}, v2 = {};
      if (kv >= 0) {
        const ushort* kb = &qkv[(size_t)kv * QKV_N + 4096 + kh * 64 + ch * 8];
        bf16x8 x1 = *(const bf16x8*)kb;
        bf16x8 x2 = *(const bf16x8*)(kb + 32);
#pragma unroll
        for (int i = 0; i < 8; ++i) {
          float2 cs = tab[(kv << 5) + ch * 8 + i];
          float a = bf2f((ushort)x1[i]), b = bf2f((ushort)x2[i]);
          v1[i] = (short)f2bf(a * cs.x - b * cs.y);
          v2[i] = (short)f2bf(b * cs.x + a * cs.y);
        }
      }
      int b1 = (row * 128 + ch * 16) ^ ((row & 7) << 4);
      int b2 = (row * 128 + (ch + 4) * 16) ^ ((row & 7) << 4);
      *(bf16x8*)(lds + b1) = v1;
      *(bf16x8*)(lds + b2) = v2;
    } else if (c < 1920) {  // VT chunk
      int cv = c - 640;
      int row = cv / 20, ch = cv - (cv / 20) * 20;
      int kv = kvw0 + ch * 8;
      bf16x8 vv = {};
      if (kv >= 0) vv = *(const bf16x8*)&vt[(size_t)(kh * 64 + row) * 2048 + kv];
      int byte = (row * 320 + ch * 16) ^ ((row & 7) << 4);
      *(bf16x8*)(lds + 20480 + byte) = vv;
    }
  }
  __syncthreads();

  char* Pw = lds + 41984 + w * 1536;
  const float snk = sinks[h];

#pragma unroll
  for (int si = 0; si < 2; ++si) {
    const ushort* qb = &qkv[(size_t)(q0 + si * 16 + r) * QKV_N + h * 64 + g * 8];
    bf16x8 qf0 = *(const bf16x8*)qb;
    bf16x8 qf1 = *(const bf16x8*)(qb + 32);
    {  // fused Q RoPE
      int s = q0 + si * 16 + r;
      bf16x8 t0, t1;
#pragma unroll
      for (int i = 0; i < 8; ++i) {
        float2 cs = tab[(s << 5) + g * 8 + i];
        float a = bf2f((ushort)qf0[i]), b = bf2f((ushort)qf1[i]);
        t0[i] = (short)f2bf(a * cs.x - b * cs.y);
        t1[i] = (short)f2bf(b * cs.x + a * cs.y);
      }
      qf0 = t0; qf1 = t1;
    }

    f32x4 S[9];
    float mx[4] = {-3e30f, -3e30f, -3e30f, -3e30f};
#pragma unroll
    for (int tt = 0; tt < 9; ++tt) {
      int kvloc = (si + tt) * 16 + r;
      int b0 = (kvloc * 128 + g * 16) ^ ((kvloc & 7) << 4);
      int b1 = (kvloc * 128 + 64 + g * 16) ^ ((kvloc & 7) << 4);
      bf16x8 kf0 = *(const bf16x8*)(lds + b0);
      bf16x8 kf1 = *(const bf16x8*)(lds + b1);
      f32x4 s = {};
      s = __builtin_amdgcn_mfma_f32_16x16x32_bf16(qf0, kf0, s, 0, 0, 0);
      s = __builtin_amdgcn_mfma_f32_16x16x32_bf16(qf1, kf1, s, 0, 0, 0);
      int kvc = kvw0 + kvloc;
#pragma unroll
      for (int j = 0; j < 4; ++j) {
        int qr = q0 + si * 16 + g * 4 + j;
        bool valid = (kvc >= 0) && (kvc <= qr) && (kvc >= qr - WIN);
        float v = valid ? s[j] * 0.125f : -1e30f;
        s[j] = v;
        mx[j] = fmaxf(mx[j], v);
      }
      S[tt] = s;
    }
#pragma unroll
    for (int off = 1; off < 16; off <<= 1)
#pragma unroll
      for (int j = 0; j < 4; ++j) mx[j] = fmaxf(mx[j], __shfl_xor(mx[j], off, 64));
    float m[4], sum[4] = {0, 0, 0, 0};
#pragma unroll
    for (int j = 0; j < 4; ++j) m[j] = fmaxf(mx[j], snk);
#pragma unroll
    for (int tt = 0; tt < 9; ++tt)
#pragma unroll
      for (int j = 0; j < 4; ++j) {
        float p = (S[tt][j] > -1e29f) ? __expf(S[tt][j] - m[j]) : 0.0f;
        S[tt][j] = p;
        sum[j] += p;
      }
#pragma unroll
    for (int off = 1; off < 16; off <<= 1)
#pragma unroll
      for (int j = 0; j < 4; ++j) sum[j] += __shfl_xor(sum[j], off, 64);
    float rinv[4];
#pragma unroll
    for (int j = 0; j < 4; ++j) rinv[j] = 1.0f / (sum[j] + __expf(snk - m[j]));

    f32x4 acc[4] = {};
#pragma unroll
    for (int ks = 0; ks < 5; ++ks) {
#pragma unroll
      for (int c2 = 0; c2 < 2; ++c2) {
        int tt = 2 * ks + c2;
#pragma unroll
        for (int j = 0; j < 4; ++j) {
          float pv = (tt <= 8) ? S[tt][j] * rinv[j] : 0.0f;
          *(ushort*)(Pw + ((g * 4 + j) * 48 + c2 * 16 + r) * 2) = f2bf(pv);
        }
      }
      bf16x8 pa = *(const bf16x8*)(Pw + (r * 48 + g * 8) * 2);
#pragma unroll
      for (int ni = 0; ni < 4; ++ni) {
        int row = ni * 16 + r;
        int byte = (row * 320 + (si * 16 + ks * 32 + g * 8) * 2) ^ ((row & 7) << 4);
        bf16x8 vb = *(const bf16x8*)(lds + 20480 + byte);
        acc[ni] = __builtin_amdgcn_mfma_f32_16x16x32_bf16(pa, vb, acc[ni], 0, 0, 0);
      }
    }
#pragma unroll
    for (int ni = 0; ni < 4; ++ni)
#pragma unroll
      for (int j = 0; j < 4; ++j)
        out[(size_t)(q0 + si * 16 + g * 4 + j) * 4096 + h * 64 + ni * 16 + r] = f2bf(acc[ni][j]);
  }
}

extern "C" void kernel_launch(void* const* d_in, const int* in_sizes, int n_in,
                              void* d_out, int out_size, void* d_ws, size_t ws_size,
                              hipStream_t stream) {
  const float* hs = (const float*)d_in[0];
  const float* Wq = (const float*)d_in[1];
  const float* bq = (const float*)d_in[2];
  const float* Wk = (const float*)d_in[3];
  const float* bk = (const float*)d_in[4];
  const float* Wv = (const float*)d_in[5];
  const float* bv = (const float*)d_in[6];
  const float* Wo = (const float*)d_in[7];
  const float* bo = (const float*)d_in[8];
  const float* sinks = (const float*)d_in[9];
  float* out = (float*)d_out;

  char* ws = (char*)d_ws;
  ushort* hs_bf   = (ushort*)(ws + 0);            // 2048x2880 bf16      11,796,480 B
  ushort* vt_g    = (ushort*)(ws + 0);            // 512x2048  bf16 (reuses hs_bf after QKV GEMM)
  ushort* wqkv_t  = (ushort*)(ws + 11796480);     // 5120x2880 bf16      29,491,200 B
  ushort* attn    = (ushort*)(ws + 11796480);     // 2048x4096 bf16 (reuses wqkv_t after QKV GEMM)
  ushort* wo_t    = (ushort*)(ws + 41287680);     // 2880x4096 bf16      23,592,960 B
  ushort* qkv     = (ushort*)(ws + 66453504);     // 2048x5120 bf16      20,971,520 B
  float*  bias_all= (float*)(ws + 87425024);      // 5120 f32
  float2* tab     = (float2*)(ws + 87445504);     // 2048x32 float2

  // fused prep: conv + transposes + biascat + ropetab (one launch)
  prep_kernel<<<9636, 256, 0, stream>>>(hs, Wq, Wk, Wv, Wo, bq, bk, bv,
                                        hs_bf, wqkv_t, wo_t, bias_all, tab);

  // QKV projection: [2048x2880] x [2880x5120] -> qkv (bf16, +bias). 16m x 32n = 512 wg, 2/CU
  gemm4w_kernel<160, true><<<512, 256, 0, stream>>>(hs_bf, wqkv_t, bias_all, qkv,
                                                    2880, 2880, 2880, 5120);
  // V transpose (into dead hs_bf region)
  vt_kernel<<<dim3(32, 8), 256, 0, stream>>>(qkv, vt_g);
  // attention with fused RoPE (into dead wqkv_t region)
  attn_kernel<<<dim3(64, 8), 512, 0, stream>>>(qkv, vt_g, sinks, tab, attn);
  // output projection: [2048x4096] x [4096x2880] -> out (f32, +bo). 16m x 18n = 288 wg
  gemm4w_kernel<160, false><<<288, 256, 0, stream>>>(attn, wo_t, bo, out,
                                                     4096, 4096, 4096, 2880);
}